// Round 1
// baseline (220.638 us; speedup 1.0000x reference)
//
#include <hip/hip_runtime.h>

// InfoCNECauchy: loss = mean_r log(sum_j sim[r,j] - sim[r,r]) - mean_r log(sim[r, r^4096])
// sim = t^2 / (d2 + t^2), d2 = ||f_r||^2 + ||f_c||^2 - 2 <f_r, f_c>, t = 0.07
//
// N2 = 8192 rows, D = 512. Fused bf16-MFMA GEMM (m97 ladder structure):
// 128x128 tiles, BK=32, global_load_lds width-16 staging, 4 waves x 4x4
// mfma_f32_16x16x32_bf16 accumulators, Cauchy epilogue fused (no 8192^2
// materialization). Diagonal excluded exactly (c==r skip).

#define N2 8192
#define DIM 512
#define T2 0.0049f /* 0.07^2 */

typedef float floatx4 __attribute__((ext_vector_type(4)));
typedef __bf16 bf16x8 __attribute__((ext_vector_type(8)));

__device__ __forceinline__ void load_to_lds16(const void* g, void* l) {
  auto gp = (const __attribute__((address_space(1))) void*)(reinterpret_cast<uintptr_t>(g));
  auto lp = (__attribute__((address_space(3))) void*)(reinterpret_cast<uintptr_t>(l));
  __builtin_amdgcn_global_load_lds(gp, lp, 16, 0, 0);
}

// ---- prep: fp32 -> bf16 copy + per-row squared norm (fp32) -------------
__global__ __launch_bounds__(256) void prep_kernel(const float* __restrict__ f,
                                                   __bf16* __restrict__ fbf,
                                                   float* __restrict__ sq) {
  const int row = blockIdx.x;
  const int t = threadIdx.x;
  const float* fr = f + (size_t)row * DIM;
  __bf16* br = fbf + (size_t)row * DIM;
  float s = 0.f;
#pragma unroll
  for (int i = 0; i < DIM / 256; ++i) {
    const int c = t + i * 256;
    const float v = fr[c];
    s += v * v;
    br[c] = (__bf16)v;
  }
#pragma unroll
  for (int off = 1; off < 64; off <<= 1) s += __shfl_xor(s, off, 64);
  __shared__ float red[4];
  if ((t & 63) == 0) red[t >> 6] = s;
  __syncthreads();
  if (t == 0) sq[row] = red[0] + red[1] + red[2] + red[3];
}

// ---- fused GEMM + Cauchy epilogue --------------------------------------
__global__ __launch_bounds__(256) void gemm_kernel(const __bf16* __restrict__ fbf,
                                                   const float* __restrict__ sq,
                                                   float* __restrict__ rowsum,
                                                   float* __restrict__ spart) {
  __shared__ __bf16 aT[128 * 32];  // [row][k], k-contig, 64 B/row
  __shared__ __bf16 bT[128 * 32];

  const int t = threadIdx.x;
  const int brow = blockIdx.y * 128;
  const int bcol = blockIdx.x * 128;
  const int lane = t & 63;
  const int w = t >> 6;
  const int wrow = (w >> 1) * 64;  // wave's 64x64 sub-tile
  const int wcol = (w & 1) * 64;
  const int q4 = lane >> 4;   // 0..3
  const int lc = lane & 15;   // 0..15

  floatx4 acc[4][4] = {};

  const int srow = t >> 2;         // staging row 0..63
  const int scol = (t & 3) * 8;    // staging col offset (elements)

  for (int kt = 0; kt < DIM / 32; ++kt) {
    const int k0 = kt * 32;
#pragma unroll
    for (int it = 0; it < 2; ++it) {
      const __bf16* ga = fbf + (size_t)(brow + srow + it * 64) * DIM + k0 + scol;
      const __bf16* gb = fbf + (size_t)(bcol + srow + it * 64) * DIM + k0 + scol;
      load_to_lds16(ga, &aT[t * 8 + it * 2048]);
      load_to_lds16(gb, &bT[t * 8 + it * 2048]);
    }
    __syncthreads();
    bf16x8 af[4], bfr[4];
#pragma unroll
    for (int mr = 0; mr < 4; ++mr)
      af[mr] = *(const bf16x8*)&aT[(wrow + mr * 16 + lc) * 32 + q4 * 8];
#pragma unroll
    for (int mc = 0; mc < 4; ++mc)
      bfr[mc] = *(const bf16x8*)&bT[(wcol + mc * 16 + lc) * 32 + q4 * 8];
#pragma unroll
    for (int mr = 0; mr < 4; ++mr)
#pragma unroll
      for (int mc = 0; mc < 4; ++mc)
        acc[mr][mc] =
            __builtin_amdgcn_mfma_f32_16x16x32_bf16(af[mr], bfr[mc], acc[mr][mc], 0, 0, 0);
    __syncthreads();
  }

  // Epilogue: C/D layout col = lane&15, row = (lane>>4)*4 + reg (m89/m91).
  float sqc[4];
#pragma unroll
  for (int mc = 0; mc < 4; ++mc) sqc[mc] = sq[bcol + wcol + mc * 16 + lc];

#pragma unroll
  for (int mr = 0; mr < 4; ++mr) {
#pragma unroll
    for (int reg = 0; reg < 4; ++reg) {
      const int r = brow + wrow + mr * 16 + q4 * 4 + reg;
      const float sr = sq[r];
      const int pc = r ^ (N2 / 2);  // partner index
      float rs = 0.f;
#pragma unroll
      for (int mc = 0; mc < 4; ++mc) {
        const int c = bcol + wcol + mc * 16 + lc;
        const float g = acc[mr][mc][reg];
        const float d2 = fmaxf(sr + sqc[mc] - 2.f * g, 0.f);
        const float s = T2 * __builtin_amdgcn_rcpf(d2 + T2);
        if (c != r) rs += s;          // exclude diagonal exactly
        if (c == pc) spart[r] = s;    // single writer per r
      }
      // reduce over the 16 lanes sharing this row (same q4 group)
#pragma unroll
      for (int off = 1; off < 16; off <<= 1) rs += __shfl_xor(rs, off, 64);
      if (lc == 0) atomicAdd(&rowsum[r], rs);
    }
  }
}

// ---- final scalar reduction --------------------------------------------
__global__ __launch_bounds__(256) void final_kernel(const float* __restrict__ rowsum,
                                                    const float* __restrict__ spart,
                                                    float* __restrict__ out) {
  const int t = threadIdx.x;
  float a = 0.f;
  for (int r = t; r < N2; r += 256) a += logf(rowsum[r]) - logf(spart[r]);
#pragma unroll
  for (int off = 1; off < 64; off <<= 1) a += __shfl_xor(a, off, 64);
  __shared__ float red[4];
  if ((t & 63) == 0) red[t >> 6] = a;
  __syncthreads();
  if (t == 0) out[0] = (red[0] + red[1] + red[2] + red[3]) * (1.0f / (float)N2);
}

extern "C" void kernel_launch(void* const* d_in, const int* in_sizes, int n_in,
                              void* d_out, int out_size, void* d_ws, size_t ws_size,
                              hipStream_t stream) {
  const float* features = (const float*)d_in[0];
  float* out = (float*)d_out;

  char* ws = (char*)d_ws;
  __bf16* fbf = (__bf16*)ws;                                  // 8 MB
  float* sq = (float*)(ws + (size_t)N2 * DIM * sizeof(__bf16));  // 32 KB
  float* rowsum = sq + N2;                                    // 32 KB
  float* spart = rowsum + N2;                                 // 32 KB

  hipMemsetAsync(rowsum, 0, N2 * sizeof(float), stream);
  prep_kernel<<<N2, 256, 0, stream>>>(features, fbf, sq);
  gemm_kernel<<<dim3(N2 / 128, N2 / 128), 256, 0, stream>>>(fbf, sq, rowsum, spart);
  final_kernel<<<1, 256, 0, stream>>>(rowsum, spart, out);
}

// Round 2
// 156.056 us; speedup vs baseline: 1.4138x; 1.4138x over previous
//
#include <hip/hip_runtime.h>

// InfoCNECauchy: loss = mean_r log(sum_{j!=r} sim[r,j]) - mean_r log(sim[r, r^4096])
// sim = t^2/(d2+t^2), d2 = ||f_r||^2 + ||f_c||^2 - 2<f_r,f_c>, t=0.07
//
// R2: exploit symmetry (2080 upper-triangle tiles instead of 4096; each
// off-diag tile feeds both rowsum[r] and rowsum[c]), and kill the 8-way LDS
// bank conflict with an XOR chunk swizzle implemented on the global-source
// side of global_load_lds (LDS side must stay lane-contiguous).

#define N2 8192
#define DIM 512
#define NT 64 /* 8192/128 tiles per dim */
#define T2 0.0049f

typedef float floatx4 __attribute__((ext_vector_type(4)));
typedef __bf16 bf16x8 __attribute__((ext_vector_type(8)));
typedef __bf16 bf16x4 __attribute__((ext_vector_type(4)));

__device__ __forceinline__ void load_to_lds16(const void* g, void* l) {
  auto gp = (const __attribute__((address_space(1))) void*)(reinterpret_cast<uintptr_t>(g));
  auto lp = (__attribute__((address_space(3))) void*)(reinterpret_cast<uintptr_t>(l));
  __builtin_amdgcn_global_load_lds(gp, lp, 16, 0, 0);
}

// ---- prep: fp32 -> bf16 + per-row squared norm; 2 rows/block, float4 ----
__global__ __launch_bounds__(256) void prep_kernel(const float* __restrict__ f,
                                                   __bf16* __restrict__ fbf,
                                                   float* __restrict__ sq) {
  const int t = threadIdx.x;
  const int row = blockIdx.x * 2 + (t >> 7);
  const int ci = (t & 127) * 4;
  const float4 v = *(const float4*)(f + (size_t)row * DIM + ci);
  bf16x4 b;
  b[0] = (__bf16)v.x; b[1] = (__bf16)v.y; b[2] = (__bf16)v.z; b[3] = (__bf16)v.w;
  *(bf16x4*)(fbf + (size_t)row * DIM + ci) = b;
  float s = v.x * v.x + v.y * v.y + v.z * v.z + v.w * v.w;
#pragma unroll
  for (int off = 1; off < 64; off <<= 1) s += __shfl_xor(s, off, 64);
  __shared__ float red[4];
  if ((t & 63) == 0) red[t >> 6] = s;
  __syncthreads();
  if ((t & 127) == 0) sq[row] = red[t >> 6] + red[(t >> 6) + 1];
}

// ---- fused GEMM (upper triangle) + Cauchy epilogue ----------------------
__global__ __launch_bounds__(256) void gemm_kernel(const __bf16* __restrict__ fbf,
                                                   const float* __restrict__ sq,
                                                   float* __restrict__ rowsum,
                                                   float* __restrict__ spart) {
  __shared__ __bf16 aT[128 * 32];  // [rowpair][swizzled 8x16B chunks]
  __shared__ __bf16 bT[128 * 32];

  // triangular decode: row `by` owns tiles bx = by..NT-1
  int idx = blockIdx.x;
  int by = 0, s0 = 0;
  while (s0 + (NT - by) <= idx) { s0 += NT - by; ++by; }
  const int bx = by + (idx - s0);
  const int brow = by * 128;
  const int bcol = bx * 128;
  const bool diag = (by == bx);

  const int t = threadIdx.x;
  const int lane = t & 63;
  const int w = t >> 6;
  const int wrow = (w >> 1) * 64;
  const int wcol = (w & 1) * 64;
  const int q4 = lane >> 4;  // 0..3
  const int lc = lane & 15;  // 0..15

  floatx4 acc[4][4] = {};

  // staging lane -> (global row, global 16B-chunk) under the XOR swizzle:
  // LDS slot (rpair, u') holds global (row = rpair*2 + (u>>2), chunk = u&3)
  // with u = u' ^ (rpair & 7).
  int grow[2], gofs[2];
#pragma unroll
  for (int it = 0; it < 2; ++it) {
    const int slot = it * 256 + t;
    const int rpair = slot >> 3;
    const int u = (slot & 7) ^ (rpair & 7);
    grow[it] = rpair * 2 + (u >> 2);
    gofs[it] = (u & 3) * 8;
  }

  // fragment-read swizzle: for (row rr, chunk q4): u = (rr&1)*4+q4,
  // u' = u ^ (rr>>1 & 7); here rr&1 = lc&1 and (rr>>1)&7 = lc>>1.
  const int up = (((lc & 1) * 4) + q4) ^ (lc >> 1);
  const int rhalf = lc >> 1;

  for (int kt = 0; kt < DIM / 32; ++kt) {
    const int k0 = kt * 32;
#pragma unroll
    for (int it = 0; it < 2; ++it) {
      load_to_lds16(fbf + (size_t)(brow + grow[it]) * DIM + k0 + gofs[it],
                    &aT[t * 8 + it * 2048]);
      load_to_lds16(fbf + (size_t)(bcol + grow[it]) * DIM + k0 + gofs[it],
                    &bT[t * 8 + it * 2048]);
    }
    __syncthreads();
    bf16x8 af[4], bfr[4];
#pragma unroll
    for (int mr = 0; mr < 4; ++mr)
      af[mr] = *(const bf16x8*)&aT[((wrow >> 1) + mr * 8 + rhalf) * 64 + up * 8];
#pragma unroll
    for (int mc = 0; mc < 4; ++mc)
      bfr[mc] = *(const bf16x8*)&bT[((wcol >> 1) + mc * 8 + rhalf) * 64 + up * 8];
#pragma unroll
    for (int mr = 0; mr < 4; ++mr)
#pragma unroll
      for (int mc = 0; mc < 4; ++mc)
        acc[mr][mc] =
            __builtin_amdgcn_mfma_f32_16x16x32_bf16(af[mr], bfr[mc], acc[mr][mc], 0, 0, 0);
    __syncthreads();
  }

  // Epilogue. C/D layout: col = lane&15, row = (lane>>4)*4 + reg.
  float sqc[4];
#pragma unroll
  for (int mc = 0; mc < 4; ++mc) sqc[mc] = sq[bcol + wcol + mc * 16 + lc];

  float cs[4] = {0.f, 0.f, 0.f, 0.f};  // column partial sums (off-diag tiles)

#pragma unroll
  for (int mr = 0; mr < 4; ++mr) {
#pragma unroll
    for (int reg = 0; reg < 4; ++reg) {
      const int r = brow + wrow + mr * 16 + q4 * 4 + reg;
      const float sr = sq[r];
      const int pc = r ^ (N2 / 2);
      float rs = 0.f;
#pragma unroll
      for (int mc = 0; mc < 4; ++mc) {
        const int c = bcol + wcol + mc * 16 + lc;
        const float g = acc[mr][mc][reg];
        const float d2 = fmaxf(sr + sqc[mc] - 2.f * g, 0.f);
        const float s = T2 * __builtin_amdgcn_rcpf(d2 + T2);
        if (c != r) rs += s;  // diagonal excluded exactly (diag tiles only)
        cs[mc] += s;          // unused on diag tiles
        if (c == pc) { spart[r] = s; spart[pc] = s; }  // off-diag only, 1 lane
      }
#pragma unroll
      for (int off = 1; off < 16; off <<= 1) rs += __shfl_xor(rs, off, 64);
      if (lc == 0) atomicAdd(&rowsum[r], rs);
    }
  }

  if (!diag) {
    // column sums: reduce the 4 q4 groups (lanes 16 apart), one atomic/col
#pragma unroll
    for (int mc = 0; mc < 4; ++mc) {
      float v = cs[mc];
      v += __shfl_xor(v, 16, 64);
      v += __shfl_xor(v, 32, 64);
      if (lane < 16) atomicAdd(&rowsum[bcol + wcol + mc * 16 + lane], v);
    }
  }
}

// ---- final scalar reduction --------------------------------------------
__global__ __launch_bounds__(256) void final_kernel(const float* __restrict__ rowsum,
                                                    const float* __restrict__ spart,
                                                    float* __restrict__ out) {
  const int t = threadIdx.x;
  float a = 0.f;
  for (int r = t; r < N2; r += 256) a += logf(rowsum[r]) - logf(spart[r]);
#pragma unroll
  for (int off = 1; off < 64; off <<= 1) a += __shfl_xor(a, off, 64);
  __shared__ float red[4];
  if ((t & 63) == 0) red[t >> 6] = a;
  __syncthreads();
  if (t == 0) out[0] = (red[0] + red[1] + red[2] + red[3]) * (1.0f / (float)N2);
}

extern "C" void kernel_launch(void* const* d_in, const int* in_sizes, int n_in,
                              void* d_out, int out_size, void* d_ws, size_t ws_size,
                              hipStream_t stream) {
  const float* features = (const float*)d_in[0];
  float* out = (float*)d_out;

  char* ws = (char*)d_ws;
  __bf16* fbf = (__bf16*)ws;                                     // 8 MB
  float* sq = (float*)(ws + (size_t)N2 * DIM * sizeof(__bf16));  // 32 KB
  float* rowsum = sq + N2;                                       // 32 KB
  float* spart = rowsum + N2;                                    // 32 KB

  hipMemsetAsync(rowsum, 0, N2 * sizeof(float), stream);
  prep_kernel<<<N2 / 2, 256, 0, stream>>>(features, fbf, sq);
  gemm_kernel<<<NT * (NT + 1) / 2, 256, 0, stream>>>(fbf, sq, rowsum, spart);
  final_kernel<<<1, 256, 0, stream>>>(rowsum, spart, out);
}